// Round 19
// baseline (235.792 us; speedup 1.0000x reference)
//
#include <hip/hip_runtime.h>
#include <hip/hip_bf16.h>
#include <cstdint>
#include <cstddef>

#define NROW 4096
#define NM ((size_t)NROW * (size_t)NROW)

// S = log2(e)/eps, eps = 0.1
#define SCONST 14.426950408889634f
#define EPS_LN2 0.0693147180559945f     // eps*ln2 = 1/S
#define ENC 461.66241308446827f         // 2*S*16  (encode scale for int16 M)
#define DEC 0.0625f                     // 1/16 decode
#define NEGBIG -3.0e38f

#if __has_builtin(__builtin_amdgcn_exp2f)
#define FEXP2(x) __builtin_amdgcn_exp2f(x)
#else
#define FEXP2(x) exp2f(x)
#endif
#if __has_builtin(__builtin_amdgcn_logf)
#define FLOG2(x) __builtin_amdgcn_logf(x)
#else
#define FLOG2(x) log2f(x)
#endif

using frag16 = __attribute__((ext_vector_type(8))) short;
using f32x4v = __attribute__((ext_vector_type(4))) float;

__device__ __forceinline__ unsigned short f2bf_rne(float f) {
    unsigned u = __builtin_bit_cast(unsigned, f);
    unsigned r = (u + 0x7fffu + ((u >> 16) & 1u)) >> 16;
    return (unsigned short)r;
}
__device__ __forceinline__ float bf2f(unsigned short h) {
    unsigned u = ((unsigned)h) << 16;
    return __builtin_bit_cast(float, u);
}

// ---------------------------------------------------------------------------
// init
// ---------------------------------------------------------------------------
__global__ void init_kernel(const float* __restrict__ x, const float* __restrict__ y,
                            const float* __restrict__ p, const float* __restrict__ q,
                            float* __restrict__ lp, float* __restrict__ lq,
                            float* __restrict__ a,
                            float* __restrict__ xn, float* __restrict__ yn) {
    int t = blockIdx.x * blockDim.x + threadIdx.x;
    if (t >= NROW) return;
    lp[t] = FLOG2(p[t]);
    lq[t] = FLOG2(q[t]);
    const float* xr = x + (size_t)t * 64;
    const float* yr = y + (size_t)t * 64;
    float sx = 0.f, sy = 0.f;
    #pragma unroll
    for (int d = 0; d < 64; ++d) {
        sx = fmaf(xr[d], xr[d], sx);
        sy = fmaf(yr[d], yr[d], sy);
    }
    xn[t] = sx; yn[t] = sy;
    a[t] = -SCONST * sy;
}

// ---------------------------------------------------------------------------
// prep: split x,y into bf16 hi/lo arrays once.
// ---------------------------------------------------------------------------
__global__ __launch_bounds__(256) void prep_bf16(const float* __restrict__ x,
                                                 const float* __restrict__ y,
                                                 uint16_t* __restrict__ xh,
                                                 uint16_t* __restrict__ xl,
                                                 uint16_t* __restrict__ yh,
                                                 uint16_t* __restrict__ yl) {
    int t = blockIdx.x * blockDim.x + threadIdx.x;
    size_t base = (size_t)t * 8;
    float4 fx0 = *(const float4*)(x + base);
    float4 fx1 = *(const float4*)(x + base + 4);
    float4 fy0 = *(const float4*)(y + base);
    float4 fy1 = *(const float4*)(y + base + 4);
    float fx[8] = {fx0.x, fx0.y, fx0.z, fx0.w, fx1.x, fx1.y, fx1.z, fx1.w};
    float fy[8] = {fy0.x, fy0.y, fy0.z, fy0.w, fy1.x, fy1.y, fy1.z, fy1.w};
    ushort hx[8], lx[8], hy[8], ly[8];
    #pragma unroll
    for (int e = 0; e < 8; ++e) {
        hx[e] = f2bf_rne(fx[e]);
        lx[e] = f2bf_rne(fx[e] - bf2f(hx[e]));
        hy[e] = f2bf_rne(fy[e]);
        ly[e] = f2bf_rne(fy[e] - bf2f(hy[e]));
    }
    *(int4*)(xh + base) = *(const int4*)hx;
    *(int4*)(xl + base) = *(const int4*)lx;
    *(int4*)(yh + base) = *(const int4*)hy;
    *(int4*)(yl + base) = *(const int4*)ly;
}

// ---------------------------------------------------------------------------
// M16 via split-bf16 MFMA, swapped operands (D^T -> 4 consecutive cols/lane).
// DIRECT short4 global stores (no LDS, no barrier): per (rt,ct) instruction
// 16 rows x 32B; the 4 ct stores fill each row's 128B L2 line completely.
// M16 values bit-identical to the LDS-staged version.
// ---------------------------------------------------------------------------
__global__ __launch_bounds__(256) void M16_mfma(const uint16_t* __restrict__ xh,
                                                const uint16_t* __restrict__ xl,
                                                const uint16_t* __restrict__ yh,
                                                const uint16_t* __restrict__ yl,
                                                int16_t* __restrict__ M16) {
    int tid = threadIdx.x;
    int lane = tid & 63;
    int wid = tid >> 6;
    int it = blockIdx.x, jt = blockIdx.y;    // XCD affinity follows row tile
    int rloc = (wid >> 1) * 64;
    int cloc = (wid & 1) * 64;
    int l15 = lane & 15;
    int g4  = lane >> 4;

    f32x4v acc[4][4];
    #pragma unroll
    for (int i = 0; i < 4; ++i)
        #pragma unroll
        for (int j = 0; j < 4; ++j)
            acc[i][j] = (f32x4v){0.f, 0.f, 0.f, 0.f};

    #pragma unroll
    for (int kk = 0; kk < 2; ++kk) {
        frag16 yhi[4], ylo[4];
        #pragma unroll
        for (int ct = 0; ct < 4; ++ct) {
            size_t off = (size_t)(jt * 128 + cloc + ct * 16 + l15) * 64 + kk * 32 + g4 * 8;
            yhi[ct] = *(const frag16*)(yh + off);
            ylo[ct] = *(const frag16*)(yl + off);
        }
        #pragma unroll
        for (int rt = 0; rt < 4; ++rt) {
            size_t off = (size_t)(it * 128 + rloc + rt * 16 + l15) * 64 + kk * 32 + g4 * 8;
            frag16 xhi = *(const frag16*)(xh + off);
            frag16 xlo = *(const frag16*)(xl + off);
            #pragma unroll
            for (int ct = 0; ct < 4; ++ct) {
                acc[rt][ct] = __builtin_amdgcn_mfma_f32_16x16x32_bf16(yhi[ct], xhi, acc[rt][ct], 0, 0, 0);
                acc[rt][ct] = __builtin_amdgcn_mfma_f32_16x16x32_bf16(ylo[ct], xhi, acc[rt][ct], 0, 0, 0);
                acc[rt][ct] = __builtin_amdgcn_mfma_f32_16x16x32_bf16(yhi[ct], xlo, acc[rt][ct], 0, 0, 0);
            }
        }
    }
    // D^T: M-row = rloc + rt*16 + l15 ; M-cols = cloc + ct*16 + g4*4 + [0..3]
    #pragma unroll
    for (int rt = 0; rt < 4; ++rt) {
        int row = it * 128 + rloc + rt * 16 + l15;
        int16_t* Mrow = M16 + (size_t)row * 4096 + jt * 128;
        #pragma unroll
        for (int ct = 0; ct < 4; ++ct) {
            int col = cloc + ct * 16 + g4 * 4;
            short4 o;
            short* op = (short*)&o;
            #pragma unroll
            for (int r = 0; r < 4; ++r) {
                float e = __builtin_rintf(ENC * acc[rt][ct][r]);
                e = fmaxf(-32767.f, fminf(32767.f, e));
                op[r] = (short)(int)e;
            }
            *(short4*)(Mrow + col) = o;
        }
    }
}

// ---------------------------------------------------------------------------
// row pass (r13-exact: 4 rows/block, 1024 blocks, XCD remap)
// ---------------------------------------------------------------------------
__global__ __launch_bounds__(256) void pass16_row(const int16_t* __restrict__ M16,
                                                  const float* __restrict__ ain,
                                                  const float* __restrict__ lp,
                                                  float* __restrict__ bt) {
    int tid = threadIdx.x;
    int lane = tid & 63, w = tid >> 6;
    int bid = blockIdx.x;
    int xcd = bid & 7;
    int idx = bid >> 3;
    int i0 = 128 * xcd + 1024 * (idx >> 5) + 4 * (idx & 31);
    const int4* r0 = (const int4*)(M16 + (size_t)i0 * 4096);
    float m[4] = {NEGBIG, NEGBIG, NEGBIG, NEGBIG};
    float s[4] = {0.f, 0.f, 0.f, 0.f};
    #pragma unroll
    for (int k = 0; k < 2; ++k) {
        int idx8 = tid + 256 * k;
        float4 a0 = *(const float4*)(ain + 8 * idx8);
        float4 a1 = *(const float4*)(ain + 8 * idx8 + 4);
        int4 v[4];
        v[0] = r0[idx8];
        v[1] = r0[idx8 + 512];
        v[2] = r0[idx8 + 1024];
        v[3] = r0[idx8 + 1536];
        #pragma unroll
        for (int r = 0; r < 4; ++r) {
            float u0 = fmaf(DEC, (float)(short)(v[r].x), a0.x);
            float u1 = fmaf(DEC, (float)(v[r].x >> 16),  a0.y);
            float u2 = fmaf(DEC, (float)(short)(v[r].y), a0.z);
            float u3 = fmaf(DEC, (float)(v[r].y >> 16),  a0.w);
            float u4 = fmaf(DEC, (float)(short)(v[r].z), a1.x);
            float u5 = fmaf(DEC, (float)(v[r].z >> 16),  a1.y);
            float u6 = fmaf(DEC, (float)(short)(v[r].w), a1.z);
            float u7 = fmaf(DEC, (float)(v[r].w >> 16),  a1.w);
            float mA = fmaxf(fmaxf(u0, u1), fmaxf(u2, u3));
            float mB = fmaxf(fmaxf(u4, u5), fmaxf(u6, u7));
            float nm = fmaxf(m[r], fmaxf(mA, mB));
            float e = ((FEXP2(u0 - nm) + FEXP2(u1 - nm)) + (FEXP2(u2 - nm) + FEXP2(u3 - nm)))
                    + ((FEXP2(u4 - nm) + FEXP2(u5 - nm)) + (FEXP2(u6 - nm) + FEXP2(u7 - nm)));
            s[r] = fmaf(s[r], FEXP2(m[r] - nm), e);
            m[r] = nm;
        }
    }
    __shared__ float sm[4][4];
    __shared__ float ss[4][4];
    #pragma unroll
    for (int r = 0; r < 4; ++r) {
        float mr = m[r], sr = s[r];
        #pragma unroll
        for (int off = 32; off >= 1; off >>= 1) {
            float om = __shfl_xor(mr, off);
            float os = __shfl_xor(sr, off);
            float nm = fmaxf(mr, om);
            sr = fmaf(sr, FEXP2(mr - nm), os * FEXP2(om - nm));
            mr = nm;
        }
        if (lane == 0) { sm[w][r] = mr; ss[w][r] = sr; }
    }
    __syncthreads();
    if (tid < 4) {
        float m0 = sm[0][tid], s0 = ss[0][tid];
        #pragma unroll
        for (int w2 = 1; w2 < 4; ++w2) {
            float m1 = sm[w2][tid], s1 = ss[w2][tid];
            float nm = fmaxf(m0, m1);
            s0 = fmaf(s0, FEXP2(m0 - nm), s1 * FEXP2(m1 - nm));
            m0 = nm;
        }
        int i = i0 + tid;
        bt[i] = lp[i] - (m0 + FLOG2(s0));
    }
}

// ---------------------------------------------------------------------------
// col pass (r13-exact, transposed grid)
// ---------------------------------------------------------------------------
__global__ __launch_bounds__(256) void pass16_col(const int16_t* __restrict__ M16,
                                                  const float* __restrict__ bt,
                                                  float* __restrict__ Lpart) {
    int tid = threadIdx.x;
    int lane = tid & 63, w = tid >> 6;
    int rg = blockIdx.x;
    int stripe = blockIdx.y;
    int col0 = stripe * 256 + lane * 4;
    int row0 = rg * 128 + w * 32;
    float mc[4] = {NEGBIG, NEGBIG, NEGBIG, NEGBIG};
    float sc[4] = {0.f, 0.f, 0.f, 0.f};
    #pragma unroll 4
    for (int r = 0; r < 32; ++r) {
        int row = row0 + r;
        float b = bt[row];
        int2 v = *(const int2*)(M16 + (size_t)row * 4096 + col0);
        float e0 = fmaf(DEC, (float)(short)(v.x), b);
        float e1 = fmaf(DEC, (float)(v.x >> 16),  b);
        float e2 = fmaf(DEC, (float)(short)(v.y), b);
        float e3 = fmaf(DEC, (float)(v.y >> 16),  b);
        float e[4] = {e0, e1, e2, e3};
        #pragma unroll
        for (int c = 0; c < 4; ++c) {
            float nm = fmaxf(mc[c], e[c]);
            sc[c] = fmaf(sc[c], FEXP2(mc[c] - nm), FEXP2(e[c] - nm));
            mc[c] = nm;
        }
    }
    __shared__ float lm[4][256];
    __shared__ float ls[4][256];
    #pragma unroll
    for (int c = 0; c < 4; ++c) {
        lm[w][lane * 4 + c] = mc[c];
        ls[w][lane * 4 + c] = sc[c];
    }
    __syncthreads();
    float m0 = lm[0][tid], s0 = ls[0][tid];
    #pragma unroll
    for (int w2 = 1; w2 < 4; ++w2) {
        float m1 = lm[w2][tid], s1 = ls[w2][tid];
        float nm = fmaxf(m0, m1);
        s0 = fmaf(s0, FEXP2(m0 - nm), s1 * FEXP2(m1 - nm));
        m0 = nm;
    }
    Lpart[(size_t)rg * 4096 + stripe * 256 + tid] = m0 + FLOG2(s0);
}

// ---------------------------------------------------------------------------
// combine 32 rowgroup partials per column -> a_j = lq_j - Lcol_j  (r13-exact)
// ---------------------------------------------------------------------------
__global__ __launch_bounds__(256) void colcombine16(const float* __restrict__ Lpart,
                                                    const float* __restrict__ lq,
                                                    float* __restrict__ aout) {
    int j = blockIdx.x * 256 + threadIdx.x;
    float v[32];
    #pragma unroll
    for (int g = 0; g < 32; ++g) v[g] = Lpart[(size_t)g * 4096 + j];
    float m[4], s[4];
    #pragma unroll
    for (int t = 0; t < 4; ++t) { m[t] = NEGBIG; s[t] = 0.f; }
    #pragma unroll
    for (int g = 0; g < 32; ++g) {
        int t = g & 3;
        float nm = fmaxf(m[t], v[g]);
        s[t] = fmaf(s[t], FEXP2(m[t] - nm), FEXP2(v[g] - nm));
        m[t] = nm;
    }
    float mm = m[0], ss = s[0];
    #pragma unroll
    for (int t = 1; t < 4; ++t) {
        float nm = fmaxf(mm, m[t]);
        ss = fmaf(ss, FEXP2(mm - nm), s[t] * FEXP2(m[t] - nm));
        mm = nm;
    }
    aout[j] = lq[j] - (mm + FLOG2(ss));
}

// ---------------------------------------------------------------------------
// pcost (r18-exact: XCD remap + non-temporal P stores)
// ---------------------------------------------------------------------------
__global__ __launch_bounds__(256) void pcost16(const int16_t* __restrict__ M16,
                                               const float* __restrict__ a,
                                               const float* __restrict__ yn,
                                               const float* __restrict__ bt,
                                               const float* __restrict__ xn,
                                               float* __restrict__ P,
                                               float* __restrict__ part) {
    int tid = threadIdx.x;
    int bid = blockIdx.x;
    int xcd = bid & 7;
    int idx = bid >> 3;
    int i = 128 * xcd + 1024 * (idx >> 7) + (idx & 127);
    float bi = bt[i];
    float xni = xn[i];
    const int4* Mrow = (const int4*)(M16 + (size_t)i * 4096);
    float* Prow = P + (size_t)i * 4096;
    float acc = 0.f;
    #pragma unroll
    for (int k = 0; k < 2; ++k) {
        int idx8 = tid + 256 * k;
        int4 v = Mrow[idx8];
        float mv[8];
        mv[0] = DEC * (float)(short)(v.x); mv[1] = DEC * (float)(v.x >> 16);
        mv[2] = DEC * (float)(short)(v.y); mv[3] = DEC * (float)(v.y >> 16);
        mv[4] = DEC * (float)(short)(v.z); mv[5] = DEC * (float)(v.z >> 16);
        mv[6] = DEC * (float)(short)(v.w); mv[7] = DEC * (float)(v.w >> 16);
        float4 a0 = *(const float4*)(a + 8 * idx8);
        float4 a1 = *(const float4*)(a + 8 * idx8 + 4);
        float4 y0 = *(const float4*)(yn + 8 * idx8);
        float4 y1 = *(const float4*)(yn + 8 * idx8 + 4);
        float av[8] = {a0.x, a0.y, a0.z, a0.w, a1.x, a1.y, a1.z, a1.w};
        float yv[8] = {y0.x, y0.y, y0.z, y0.w, y1.x, y1.y, y1.z, y1.w};
        #pragma unroll
        for (int e = 0; e < 8; ++e) {
            float Pv = FEXP2(bi + av[e] + mv[e]);
            float Cv = xni + yv[e] - EPS_LN2 * mv[e];
            __builtin_nontemporal_store(Pv, &Prow[8 * idx8 + e]);
            acc = fmaf(Pv, Cv, acc);
        }
    }
    #pragma unroll
    for (int off = 32; off >= 1; off >>= 1) acc += __shfl_xor(acc, off);
    __shared__ float sw[4];
    if ((tid & 63) == 0) sw[tid >> 6] = acc;
    __syncthreads();
    if (tid == 0) part[blockIdx.x] = (sw[0] + sw[1]) + (sw[2] + sw[3]);
}

__global__ __launch_bounds__(256) void reduce_kernel(const float* __restrict__ part,
                                                     float* __restrict__ out0) {
    int tid = threadIdx.x;
    float acc = 0.f;
    #pragma unroll
    for (int k = 0; k < 16; ++k) acc += part[tid + 256 * k];
    #pragma unroll
    for (int off = 32; off >= 1; off >>= 1) acc += __shfl_xor(acc, off);
    __shared__ float sw[4];
    if ((tid & 63) == 0) sw[tid >> 6] = acc;
    __syncthreads();
    if (tid == 0) out0[0] = (sw[0] + sw[1]) + (sw[2] + sw[3]);
}

// ---------------------------------------------------------------------------
extern "C" void kernel_launch(void* const* d_in, const int* in_sizes, int n_in,
                              void* d_out, int out_size, void* d_ws, size_t ws_size,
                              hipStream_t stream) {
    const float* x = (const float*)d_in[0];
    const float* y = (const float*)d_in[1];
    const float* p = (const float*)d_in[2];
    const float* q = (const float*)d_in[3];
    float* out = (float*)d_out;
    char* ws = (char*)d_ws;

    float* lp    = (float*)(ws + 0 * 16384);
    float* lq    = (float*)(ws + 1 * 16384);
    float* a     = (float*)(ws + 2 * 16384);
    float* bt    = (float*)(ws + 3 * 16384);
    float* xn    = (float*)(ws + 4 * 16384);
    float* yn    = (float*)(ws + 5 * 16384);
    float* part  = (float*)(ws + 6 * 16384);
    float* Lpart = (float*)(ws + (1 << 20));           // 512 KB
    uint16_t* xh = (uint16_t*)(ws + (4u << 20));       // 512 KB each
    uint16_t* xl = (uint16_t*)(ws + (4u << 20) + 1 * 524288);
    uint16_t* yh = (uint16_t*)(ws + (4u << 20) + 2 * 524288);
    uint16_t* yl = (uint16_t*)(ws + (4u << 20) + 3 * 524288);
    int16_t* M16 = (int16_t*)(ws + (16u << 20));       // 32 MB

    init_kernel<<<16, 256, 0, stream>>>(x, y, p, q, lp, lq, a, xn, yn);
    prep_bf16<<<128, 256, 0, stream>>>(x, y, xh, xl, yh, yl);
    M16_mfma<<<dim3(32, 32), 256, 0, stream>>>(xh, xl, yh, yl, M16);

    for (int iter = 0; iter < 10; ++iter) {
        pass16_row<<<1024, 256, 0, stream>>>(M16, a, lp, bt);
        pass16_col<<<dim3(32, 16), 256, 0, stream>>>(M16, bt, Lpart);
        colcombine16<<<16, 256, 0, stream>>>(Lpart, lq, a);
    }

    pcost16<<<4096, 256, 0, stream>>>(M16, a, yn, bt, xn, out + 1, part);
    reduce_kernel<<<1, 256, 0, stream>>>(part, out);
}

// Round 20
// 233.699 us; speedup vs baseline: 1.0090x; 1.0090x over previous
//
#include <hip/hip_runtime.h>
#include <hip/hip_bf16.h>
#include <cstdint>
#include <cstddef>

#define NROW 4096
#define NM ((size_t)NROW * (size_t)NROW)

// S = log2(e)/eps, eps = 0.1
#define SCONST 14.426950408889634f
#define EPS_LN2 0.0693147180559945f     // eps*ln2 = 1/S
#define ENC 461.66241308446827f         // 2*S*16  (encode scale for int16 M)
#define DEC 0.0625f                     // 1/16 decode
#define NEGBIG -3.0e38f

#if __has_builtin(__builtin_amdgcn_exp2f)
#define FEXP2(x) __builtin_amdgcn_exp2f(x)
#else
#define FEXP2(x) exp2f(x)
#endif
#if __has_builtin(__builtin_amdgcn_logf)
#define FLOG2(x) __builtin_amdgcn_logf(x)
#else
#define FLOG2(x) log2f(x)
#endif

using frag16 = __attribute__((ext_vector_type(8))) short;
using f32x4v = __attribute__((ext_vector_type(4))) float;

__device__ __forceinline__ unsigned short f2bf_rne(float f) {
    unsigned u = __builtin_bit_cast(unsigned, f);
    unsigned r = (u + 0x7fffu + ((u >> 16) & 1u)) >> 16;
    return (unsigned short)r;
}
__device__ __forceinline__ float bf2f(unsigned short h) {
    unsigned u = ((unsigned)h) << 16;
    return __builtin_bit_cast(float, u);
}

// ---------------------------------------------------------------------------
// init
// ---------------------------------------------------------------------------
__global__ void init_kernel(const float* __restrict__ x, const float* __restrict__ y,
                            const float* __restrict__ p, const float* __restrict__ q,
                            float* __restrict__ lp, float* __restrict__ lq,
                            float* __restrict__ a,
                            float* __restrict__ xn, float* __restrict__ yn) {
    int t = blockIdx.x * blockDim.x + threadIdx.x;
    if (t >= NROW) return;
    lp[t] = FLOG2(p[t]);
    lq[t] = FLOG2(q[t]);
    const float* xr = x + (size_t)t * 64;
    const float* yr = y + (size_t)t * 64;
    float sx = 0.f, sy = 0.f;
    #pragma unroll
    for (int d = 0; d < 64; ++d) {
        sx = fmaf(xr[d], xr[d], sx);
        sy = fmaf(yr[d], yr[d], sy);
    }
    xn[t] = sx; yn[t] = sy;
    a[t] = -SCONST * sy;
}

// ---------------------------------------------------------------------------
// prep: split x,y into bf16 hi/lo arrays once.
// ---------------------------------------------------------------------------
__global__ __launch_bounds__(256) void prep_bf16(const float* __restrict__ x,
                                                 const float* __restrict__ y,
                                                 uint16_t* __restrict__ xh,
                                                 uint16_t* __restrict__ xl,
                                                 uint16_t* __restrict__ yh,
                                                 uint16_t* __restrict__ yl) {
    int t = blockIdx.x * blockDim.x + threadIdx.x;
    size_t base = (size_t)t * 8;
    float4 fx0 = *(const float4*)(x + base);
    float4 fx1 = *(const float4*)(x + base + 4);
    float4 fy0 = *(const float4*)(y + base);
    float4 fy1 = *(const float4*)(y + base + 4);
    float fx[8] = {fx0.x, fx0.y, fx0.z, fx0.w, fx1.x, fx1.y, fx1.z, fx1.w};
    float fy[8] = {fy0.x, fy0.y, fy0.z, fy0.w, fy1.x, fy1.y, fy1.z, fy1.w};
    ushort hx[8], lx[8], hy[8], ly[8];
    #pragma unroll
    for (int e = 0; e < 8; ++e) {
        hx[e] = f2bf_rne(fx[e]);
        lx[e] = f2bf_rne(fx[e] - bf2f(hx[e]));
        hy[e] = f2bf_rne(fy[e]);
        ly[e] = f2bf_rne(fy[e] - bf2f(hy[e]));
    }
    *(int4*)(xh + base) = *(const int4*)hx;
    *(int4*)(xl + base) = *(const int4*)lx;
    *(int4*)(yh + base) = *(const int4*)hy;
    *(int4*)(yl + base) = *(const int4*)ly;
}

// ---------------------------------------------------------------------------
// M16 via split-bf16 MFMA (r13-exact: LDS-staged coalesced stores)
// ---------------------------------------------------------------------------
__global__ __launch_bounds__(256) void M16_mfma(const uint16_t* __restrict__ xh,
                                                const uint16_t* __restrict__ xl,
                                                const uint16_t* __restrict__ yh,
                                                const uint16_t* __restrict__ yl,
                                                int16_t* __restrict__ M16) {
    __shared__ int16_t tile[128][136];
    int tid = threadIdx.x;
    int lane = tid & 63;
    int wid = tid >> 6;
    int it = blockIdx.x, jt = blockIdx.y;
    int rloc = (wid >> 1) * 64;
    int cloc = (wid & 1) * 64;
    int l15 = lane & 15;
    int g4  = lane >> 4;

    f32x4v acc[4][4];
    #pragma unroll
    for (int i = 0; i < 4; ++i)
        #pragma unroll
        for (int j = 0; j < 4; ++j)
            acc[i][j] = (f32x4v){0.f, 0.f, 0.f, 0.f};

    #pragma unroll
    for (int kk = 0; kk < 2; ++kk) {
        frag16 yhi[4], ylo[4];
        #pragma unroll
        for (int ct = 0; ct < 4; ++ct) {
            size_t off = (size_t)(jt * 128 + cloc + ct * 16 + l15) * 64 + kk * 32 + g4 * 8;
            yhi[ct] = *(const frag16*)(yh + off);
            ylo[ct] = *(const frag16*)(yl + off);
        }
        #pragma unroll
        for (int rt = 0; rt < 4; ++rt) {
            size_t off = (size_t)(it * 128 + rloc + rt * 16 + l15) * 64 + kk * 32 + g4 * 8;
            frag16 xhi = *(const frag16*)(xh + off);
            frag16 xlo = *(const frag16*)(xl + off);
            #pragma unroll
            for (int ct = 0; ct < 4; ++ct) {
                acc[rt][ct] = __builtin_amdgcn_mfma_f32_16x16x32_bf16(yhi[ct], xhi, acc[rt][ct], 0, 0, 0);
                acc[rt][ct] = __builtin_amdgcn_mfma_f32_16x16x32_bf16(ylo[ct], xhi, acc[rt][ct], 0, 0, 0);
                acc[rt][ct] = __builtin_amdgcn_mfma_f32_16x16x32_bf16(yhi[ct], xlo, acc[rt][ct], 0, 0, 0);
            }
        }
    }
    #pragma unroll
    for (int rt = 0; rt < 4; ++rt) {
        int row = rloc + rt * 16 + l15;
        #pragma unroll
        for (int ct = 0; ct < 4; ++ct) {
            int col = cloc + ct * 16 + g4 * 4;
            short4 o;
            short* op = (short*)&o;
            #pragma unroll
            for (int r = 0; r < 4; ++r) {
                float e = __builtin_rintf(ENC * acc[rt][ct][r]);
                e = fmaxf(-32767.f, fminf(32767.f, e));
                op[r] = (short)(int)e;
            }
            *(short4*)&tile[row][col] = o;
        }
    }
    __syncthreads();
    #pragma unroll
    for (int pass = 0; pass < 8; ++pass) {
        int row = (tid >> 4) + 16 * pass;
        int c16 = (tid & 15) * 8;
        int4 v = *(const int4*)&tile[row][c16];
        *(int4*)(M16 + (size_t)(it * 128 + row) * 4096 + jt * 128 + c16) = v;
    }
}

// ---------------------------------------------------------------------------
// row pass (r13-exact: 4 rows/block, 1024 blocks, XCD remap)
// ---------------------------------------------------------------------------
__global__ __launch_bounds__(256) void pass16_row(const int16_t* __restrict__ M16,
                                                  const float* __restrict__ ain,
                                                  const float* __restrict__ lp,
                                                  float* __restrict__ bt) {
    int tid = threadIdx.x;
    int lane = tid & 63, w = tid >> 6;
    int bid = blockIdx.x;
    int xcd = bid & 7;
    int idx = bid >> 3;
    int i0 = 128 * xcd + 1024 * (idx >> 5) + 4 * (idx & 31);
    const int4* r0 = (const int4*)(M16 + (size_t)i0 * 4096);
    float m[4] = {NEGBIG, NEGBIG, NEGBIG, NEGBIG};
    float s[4] = {0.f, 0.f, 0.f, 0.f};
    #pragma unroll
    for (int k = 0; k < 2; ++k) {
        int idx8 = tid + 256 * k;
        float4 a0 = *(const float4*)(ain + 8 * idx8);
        float4 a1 = *(const float4*)(ain + 8 * idx8 + 4);
        int4 v[4];
        v[0] = r0[idx8];
        v[1] = r0[idx8 + 512];
        v[2] = r0[idx8 + 1024];
        v[3] = r0[idx8 + 1536];
        #pragma unroll
        for (int r = 0; r < 4; ++r) {
            float u0 = fmaf(DEC, (float)(short)(v[r].x), a0.x);
            float u1 = fmaf(DEC, (float)(v[r].x >> 16),  a0.y);
            float u2 = fmaf(DEC, (float)(short)(v[r].y), a0.z);
            float u3 = fmaf(DEC, (float)(v[r].y >> 16),  a0.w);
            float u4 = fmaf(DEC, (float)(short)(v[r].z), a1.x);
            float u5 = fmaf(DEC, (float)(v[r].z >> 16),  a1.y);
            float u6 = fmaf(DEC, (float)(short)(v[r].w), a1.z);
            float u7 = fmaf(DEC, (float)(v[r].w >> 16),  a1.w);
            float mA = fmaxf(fmaxf(u0, u1), fmaxf(u2, u3));
            float mB = fmaxf(fmaxf(u4, u5), fmaxf(u6, u7));
            float nm = fmaxf(m[r], fmaxf(mA, mB));
            float e = ((FEXP2(u0 - nm) + FEXP2(u1 - nm)) + (FEXP2(u2 - nm) + FEXP2(u3 - nm)))
                    + ((FEXP2(u4 - nm) + FEXP2(u5 - nm)) + (FEXP2(u6 - nm) + FEXP2(u7 - nm)));
            s[r] = fmaf(s[r], FEXP2(m[r] - nm), e);
            m[r] = nm;
        }
    }
    __shared__ float sm[4][4];
    __shared__ float ss[4][4];
    #pragma unroll
    for (int r = 0; r < 4; ++r) {
        float mr = m[r], sr = s[r];
        #pragma unroll
        for (int off = 32; off >= 1; off >>= 1) {
            float om = __shfl_xor(mr, off);
            float os = __shfl_xor(sr, off);
            float nm = fmaxf(mr, om);
            sr = fmaf(sr, FEXP2(mr - nm), os * FEXP2(om - nm));
            mr = nm;
        }
        if (lane == 0) { sm[w][r] = mr; ss[w][r] = sr; }
    }
    __syncthreads();
    if (tid < 4) {
        float m0 = sm[0][tid], s0 = ss[0][tid];
        #pragma unroll
        for (int w2 = 1; w2 < 4; ++w2) {
            float m1 = sm[w2][tid], s1 = ss[w2][tid];
            float nm = fmaxf(m0, m1);
            s0 = fmaf(s0, FEXP2(m0 - nm), s1 * FEXP2(m1 - nm));
            m0 = nm;
        }
        int i = i0 + tid;
        bt[i] = lp[i] - (m0 + FLOG2(s0));
    }
}

// ---------------------------------------------------------------------------
// col pass (r13-exact, transposed grid)
// ---------------------------------------------------------------------------
__global__ __launch_bounds__(256) void pass16_col(const int16_t* __restrict__ M16,
                                                  const float* __restrict__ bt,
                                                  float* __restrict__ Lpart) {
    int tid = threadIdx.x;
    int lane = tid & 63, w = tid >> 6;
    int rg = blockIdx.x;
    int stripe = blockIdx.y;
    int col0 = stripe * 256 + lane * 4;
    int row0 = rg * 128 + w * 32;
    float mc[4] = {NEGBIG, NEGBIG, NEGBIG, NEGBIG};
    float sc[4] = {0.f, 0.f, 0.f, 0.f};
    #pragma unroll 4
    for (int r = 0; r < 32; ++r) {
        int row = row0 + r;
        float b = bt[row];
        int2 v = *(const int2*)(M16 + (size_t)row * 4096 + col0);
        float e0 = fmaf(DEC, (float)(short)(v.x), b);
        float e1 = fmaf(DEC, (float)(v.x >> 16),  b);
        float e2 = fmaf(DEC, (float)(short)(v.y), b);
        float e3 = fmaf(DEC, (float)(v.y >> 16),  b);
        float e[4] = {e0, e1, e2, e3};
        #pragma unroll
        for (int c = 0; c < 4; ++c) {
            float nm = fmaxf(mc[c], e[c]);
            sc[c] = fmaf(sc[c], FEXP2(mc[c] - nm), FEXP2(e[c] - nm));
            mc[c] = nm;
        }
    }
    __shared__ float lm[4][256];
    __shared__ float ls[4][256];
    #pragma unroll
    for (int c = 0; c < 4; ++c) {
        lm[w][lane * 4 + c] = mc[c];
        ls[w][lane * 4 + c] = sc[c];
    }
    __syncthreads();
    float m0 = lm[0][tid], s0 = ls[0][tid];
    #pragma unroll
    for (int w2 = 1; w2 < 4; ++w2) {
        float m1 = lm[w2][tid], s1 = ls[w2][tid];
        float nm = fmaxf(m0, m1);
        s0 = fmaf(s0, FEXP2(m0 - nm), s1 * FEXP2(m1 - nm));
        m0 = nm;
    }
    Lpart[(size_t)rg * 4096 + stripe * 256 + tid] = m0 + FLOG2(s0);
}

// ---------------------------------------------------------------------------
// combine 32 rowgroup partials per column -> a_j = lq_j - Lcol_j
// ---------------------------------------------------------------------------
__global__ __launch_bounds__(256) void colcombine16(const float* __restrict__ Lpart,
                                                    const float* __restrict__ lq,
                                                    float* __restrict__ aout) {
    int j = blockIdx.x * 256 + threadIdx.x;
    float v[32];
    #pragma unroll
    for (int g = 0; g < 32; ++g) v[g] = Lpart[(size_t)g * 4096 + j];
    float m[4], s[4];
    #pragma unroll
    for (int t = 0; t < 4; ++t) { m[t] = NEGBIG; s[t] = 0.f; }
    #pragma unroll
    for (int g = 0; g < 32; ++g) {
        int t = g & 3;
        float nm = fmaxf(m[t], v[g]);
        s[t] = fmaf(s[t], FEXP2(m[t] - nm), FEXP2(v[g] - nm));
        m[t] = nm;
    }
    float mm = m[0], ss = s[0];
    #pragma unroll
    for (int t = 1; t < 4; ++t) {
        float nm = fmaxf(mm, m[t]);
        ss = fmaf(ss, FEXP2(mm - nm), s[t] * FEXP2(m[t] - nm));
        mm = nm;
    }
    aout[j] = lq[j] - (mm + FLOG2(ss));
}

// ---------------------------------------------------------------------------
// pcost (XCD remap + non-temporal P stores)
// ---------------------------------------------------------------------------
__global__ __launch_bounds__(256) void pcost16(const int16_t* __restrict__ M16,
                                               const float* __restrict__ a,
                                               const float* __restrict__ yn,
                                               const float* __restrict__ bt,
                                               const float* __restrict__ xn,
                                               float* __restrict__ P,
                                               float* __restrict__ part) {
    int tid = threadIdx.x;
    int bid = blockIdx.x;
    int xcd = bid & 7;
    int idx = bid >> 3;
    int i = 128 * xcd + 1024 * (idx >> 7) + (idx & 127);
    float bi = bt[i];
    float xni = xn[i];
    const int4* Mrow = (const int4*)(M16 + (size_t)i * 4096);
    float* Prow = P + (size_t)i * 4096;
    float acc = 0.f;
    #pragma unroll
    for (int k = 0; k < 2; ++k) {
        int idx8 = tid + 256 * k;
        int4 v = Mrow[idx8];
        float mv[8];
        mv[0] = DEC * (float)(short)(v.x); mv[1] = DEC * (float)(v.x >> 16);
        mv[2] = DEC * (float)(short)(v.y); mv[3] = DEC * (float)(v.y >> 16);
        mv[4] = DEC * (float)(short)(v.z); mv[5] = DEC * (float)(v.z >> 16);
        mv[6] = DEC * (float)(short)(v.w); mv[7] = DEC * (float)(v.w >> 16);
        float4 a0 = *(const float4*)(a + 8 * idx8);
        float4 a1 = *(const float4*)(a + 8 * idx8 + 4);
        float4 y0 = *(const float4*)(yn + 8 * idx8);
        float4 y1 = *(const float4*)(yn + 8 * idx8 + 4);
        float av[8] = {a0.x, a0.y, a0.z, a0.w, a1.x, a1.y, a1.z, a1.w};
        float yv[8] = {y0.x, y0.y, y0.z, y0.w, y1.x, y1.y, y1.z, y1.w};
        #pragma unroll
        for (int e = 0; e < 8; ++e) {
            float Pv = FEXP2(bi + av[e] + mv[e]);
            float Cv = xni + yv[e] - EPS_LN2 * mv[e];
            __builtin_nontemporal_store(Pv, &Prow[8 * idx8 + e]);
            acc = fmaf(Pv, Cv, acc);
        }
    }
    #pragma unroll
    for (int off = 32; off >= 1; off >>= 1) acc += __shfl_xor(acc, off);
    __shared__ float sw[4];
    if ((tid & 63) == 0) sw[tid >> 6] = acc;
    __syncthreads();
    if (tid == 0) part[blockIdx.x] = (sw[0] + sw[1]) + (sw[2] + sw[3]);
}

__global__ __launch_bounds__(256) void reduce_kernel(const float* __restrict__ part,
                                                     float* __restrict__ out0) {
    int tid = threadIdx.x;
    float acc = 0.f;
    #pragma unroll
    for (int k = 0; k < 16; ++k) acc += part[tid + 256 * k];
    #pragma unroll
    for (int off = 32; off >= 1; off >>= 1) acc += __shfl_xor(acc, off);
    __shared__ float sw[4];
    if ((tid & 63) == 0) sw[tid >> 6] = acc;
    __syncthreads();
    if (tid == 0) out0[0] = (sw[0] + sw[1]) + (sw[2] + sw[3]);
}

// ---------------------------------------------------------------------------
extern "C" void kernel_launch(void* const* d_in, const int* in_sizes, int n_in,
                              void* d_out, int out_size, void* d_ws, size_t ws_size,
                              hipStream_t stream) {
    const float* x = (const float*)d_in[0];
    const float* y = (const float*)d_in[1];
    const float* p = (const float*)d_in[2];
    const float* q = (const float*)d_in[3];
    float* out = (float*)d_out;
    char* ws = (char*)d_ws;

    float* lp    = (float*)(ws + 0 * 16384);
    float* lq    = (float*)(ws + 1 * 16384);
    float* a     = (float*)(ws + 2 * 16384);
    float* bt    = (float*)(ws + 3 * 16384);
    float* xn    = (float*)(ws + 4 * 16384);
    float* yn    = (float*)(ws + 5 * 16384);
    float* part  = (float*)(ws + 6 * 16384);
    float* Lpart = (float*)(ws + (1 << 20));           // 512 KB
    uint16_t* xh = (uint16_t*)(ws + (4u << 20));       // 512 KB each
    uint16_t* xl = (uint16_t*)(ws + (4u << 20) + 1 * 524288);
    uint16_t* yh = (uint16_t*)(ws + (4u << 20) + 2 * 524288);
    uint16_t* yl = (uint16_t*)(ws + (4u << 20) + 3 * 524288);
    int16_t* M16 = (int16_t*)(ws + (16u << 20));       // 32 MB

    init_kernel<<<16, 256, 0, stream>>>(x, y, p, q, lp, lq, a, xn, yn);
    prep_bf16<<<128, 256, 0, stream>>>(x, y, xh, xl, yh, yl);
    M16_mfma<<<dim3(32, 32), 256, 0, stream>>>(xh, xl, yh, yl, M16);

    for (int iter = 0; iter < 10; ++iter) {
        pass16_row<<<1024, 256, 0, stream>>>(M16, a, lp, bt);
        pass16_col<<<dim3(32, 16), 256, 0, stream>>>(M16, bt, Lpart);
        colcombine16<<<16, 256, 0, stream>>>(Lpart, lq, a);
    }

    pcost16<<<4096, 256, 0, stream>>>(M16, a, yn, bt, xn, out + 1, part);
    reduce_kernel<<<1, 256, 0, stream>>>(part, out);
}